// Round 6
// baseline (1627.268 us; speedup 1.0000x reference)
//
#include <hip/hip_runtime.h>

#define SEQL 1024
#define BATCHN 128
#define UNITS 256
#define INDIM 128
#define G3 768   // r|u|h gate columns

typedef __attribute__((ext_vector_type(8))) short short8;
typedef __attribute__((ext_vector_type(4))) short short4v;
typedef __attribute__((ext_vector_type(4))) float floatx4;

#define NL2E  -1.4426950408889634f   // -log2(e): r,u gate scale
#define PL2E2  2.8853900817779268f   //  2*log2(e): h gate scale

#define HSTRIDE 272                  // compact h row stride (shorts), breaks bank alias

// ctl[] layout (ints, after the 8192 flags):
//  [0]=head work counter  [1]=tail work counter  [3]=rnn-ready count
//  [4..35]=rnn CU keys    [36..67]=rnn progress (step t per wg)
#define C_HEAD 0
#define C_TAIL 1
#define C_RDY  3
#define C_KEY  4
#define C_PROG 36
#define TAIL_CAP 48
#define PARK_MARGIN 128

__device__ __forceinline__ short f2bf(float f) {
  unsigned u = __float_as_uint(f);
  u += 0x7fff + ((u >> 16) & 1);   // round-to-nearest-even
  return (short)(u >> 16);
}
__device__ __forceinline__ float bf2f(unsigned short s) {
  return __uint_as_float(((unsigned)s) << 16);
}
__device__ __forceinline__ float fexp2(float x) {
#if __has_builtin(__builtin_amdgcn_exp2f)
  return __builtin_amdgcn_exp2f(x);
#else
  return __expf(0.6931471805599453f * x);
#endif
}
__device__ __forceinline__ float frcp(float x) {
#if __has_builtin(__builtin_amdgcn_rcpf)
  return __builtin_amdgcn_rcpf(x);
#else
  return 1.f / x;
#endif
}

// LDS-only barrier: orders ds ops without draining vmcnt.
#define LDS_BARRIER() do {                                   \
    asm volatile("s_waitcnt lgkmcnt(0)" ::: "memory");       \
    __builtin_amdgcn_s_barrier();                            \
    asm volatile("" ::: "memory");                           \
  } while (0)

// Acquire-spin on a producer flag.
__device__ __forceinline__ void acq_spin(const int* p) {
  while (__hip_atomic_load(p, __ATOMIC_ACQUIRE, __HIP_MEMORY_SCOPE_AGENT) == 0)
    __builtin_amdgcn_s_sleep(8);
}

// CU identity key: HW_ID (hwreg 4) bits [15:8] = CU_ID/SH_ID/SE_ID on
// gfx9-lineage, plus XCC_ID (hwreg 20, gfx940+). Wave-uniform per CU.
// If the field layout differs on gfx950 this degrades to never-match
// (status-quo perf), never to incorrectness.
__device__ __forceinline__ unsigned cu_key() {
  unsigned hwid, xcc;
  asm volatile("s_getreg_b32 %0, hwreg(4)\n\t"
               "s_getreg_b32 %1, hwreg(20)"
               : "=s"(hwid), "=s"(xcc));
  return ((xcc & 0xffu) << 16) | (hwid & 0xff00u);
}

// ---------------------------------------------------------------------------
// Kernel A: weight prep (unchanged math) + zeroing flags and scheduler ctl.
// ---------------------------------------------------------------------------
__global__ void prep_kernel(const float* __restrict__ iw,   // (128,1792)
                            const float* __restrict__ hw,   // (256,768)
                            short* __restrict__ WcB, short* __restrict__ WhB,
                            int* __restrict__ flags) {
  int idx = blockIdx.x * 256 + threadIdx.x;
  const int WCN = 384 * G3;
  if (idx < WCN) {
    int k = idx / G3, n = idx % G3;
    int i = k & 127, blkk = k >> 7;      // 0:x_t 1:x_{t-1} 2:x_{t-2}
    int gsel = n >> 8, c = n & 255;      // 0:r 1:u 2:h
    const float* row = iw + (size_t)i * 1792;
    float v;
    if (blkk == 0) {
      v = (gsel == 0) ? row[c] + row[768 + c] + row[1280 + c]
        : (gsel == 1) ? row[256 + c] + row[1024 + c] + row[1536 + c]
                      : row[512 + c];
    } else if (blkk == 1) {
      v = (gsel == 0) ? -(row[768 + c] + 2.f * row[1280 + c])
        : (gsel == 1) ? -(row[1024 + c] + 2.f * row[1536 + c])
                      : 0.f;
    } else {
      v = (gsel == 0) ? row[1280 + c]
        : (gsel == 1) ? row[1536 + c]
                      : 0.f;
    }
    v *= (gsel == 2) ? PL2E2 : NL2E;
    int kk = k >> 5, q = (k >> 3) & 3, j = k & 7;
    WcB[(((n * 12 + kk) * 4 + q) * 8) + j] = f2bf(v);
  } else {
    idx -= WCN;
    if (idx < 256 * G3) {
      int k = idx / G3, n = idx % G3;
      float v = hw[(size_t)k * G3 + n] * ((n >> 8) == 2 ? PL2E2 : NL2E);
      int kk = k >> 5, q = (k >> 3) & 3, j = k & 7;
      WhB[(((n * 8 + kk) * 4 + q) * 8) + j] = f2bf(v);
    } else {
      idx -= 256 * G3;
      if (idx < SEQL * 8 + 128) flags[idx] = 0;   // flags + ctl
    }
  }
}

// ---------------------------------------------------------------------------
// Fused kernel: blocks 0..31 = persistent recurrence (consumer); the other
// 4096 blocks = input projection (producer) via work counters.
// R6: proj blocks that land on a CU hosting an rnn block grab a TAIL work
// item (largest t, consumed last) and PARK (barrier-dormant, thread-0
// sleep-poll on rnn progress) until the consumer is within PARK_MARGIN
// steps. The rnn CU therefore runs uncontended: R4/R5 showed co-resident
// proj waves steal ~45% of the matrix pipe and s_setprio cannot prevent it
// (non-preemptive pipe occupancy). Tail grabs capped at TAIL_CAP so >=464
// head workers always advance production (deadlock-free by induction on t).
// ---------------------------------------------------------------------------
__global__ __launch_bounds__(512, 2) void fused_kernel(
    const float* __restrict__ x, const short* __restrict__ WcB,
    const float* __restrict__ bias, unsigned* __restrict__ pre2,
    const short* __restrict__ WhB, float* __restrict__ out,
    int* __restrict__ flags) {
  __shared__ __align__(16) short smem[12288];   // 24 KB: proj 2x6144, rnn 2176
  __shared__ int bctl[2];                       // [0]=work item, [1]=polite
  int* ctl = flags + SEQL * 8;

  if (blockIdx.x >= 32) {
    // =================== proj role ===================
    const int tid = threadIdx.x;
    if (tid == 0) {
      // bounded wait for the 32 rnn blocks to publish CU keys (~1 us)
      for (int it = 0; it < 2000; ++it) {
        if (__hip_atomic_load(&ctl[C_RDY], __ATOMIC_ACQUIRE,
                              __HIP_MEMORY_SCOPE_AGENT) >= 32) break;
        __builtin_amdgcn_s_sleep(2);
      }
      unsigned k = cu_key();
      int polite = 0;
      for (int i = 0; i < 32; ++i)
        if ((unsigned)__hip_atomic_load(&ctl[C_KEY + i], __ATOMIC_RELAXED,
                                        __HIP_MEMORY_SCOPE_AGENT) == k)
          polite = 1;
      int item;
      if (polite) {
        int n = __hip_atomic_fetch_add(&ctl[C_TAIL], 1, __ATOMIC_RELAXED,
                                       __HIP_MEMORY_SCOPE_AGENT);
        if (n < TAIL_CAP) {
          item = 4095 - n;
        } else {
          polite = 0;
          item = __hip_atomic_fetch_add(&ctl[C_HEAD], 1, __ATOMIC_RELAXED,
                                        __HIP_MEMORY_SCOPE_AGENT);
        }
      } else {
        item = __hip_atomic_fetch_add(&ctl[C_HEAD], 1, __ATOMIC_RELAXED,
                                      __HIP_MEMORY_SCOPE_AGENT);
      }
      bctl[0] = item; bctl[1] = polite;
    }
    __syncthreads();
    const int item = bctl[0];
    const int tpair = item >> 3, mt = item & 7;

    if (bctl[1]) {
      // park: thread 0 polls consumer progress; 511 threads dormant here.
      if (tid == 0) {
        const int thr = 2 * tpair - PARK_MARGIN;
        for (int it = 0; it < (1 << 20); ++it) {
          int m0 = __hip_atomic_load(&ctl[C_PROG + mt * 4 + 0], __ATOMIC_RELAXED, __HIP_MEMORY_SCOPE_AGENT);
          int m1 = __hip_atomic_load(&ctl[C_PROG + mt * 4 + 1], __ATOMIC_RELAXED, __HIP_MEMORY_SCOPE_AGENT);
          int m2 = __hip_atomic_load(&ctl[C_PROG + mt * 4 + 2], __ATOMIC_RELAXED, __HIP_MEMORY_SCOPE_AGENT);
          int m3 = __hip_atomic_load(&ctl[C_PROG + mt * 4 + 3], __ATOMIC_RELAXED, __HIP_MEMORY_SCOPE_AGENT);
          int m = min(min(m0, m1), min(m2, m3));
          if (m >= thr) break;
          __builtin_amdgcn_s_sleep(8);
        }
      }
      __syncthreads();
    }

    const int half = tid >> 8, htid = tid & 255;
    const int t = tpair * 2 + half;
    short* xF = smem + half * 6144;             // [kk][lane][8] bf16 A-frags

#pragma unroll
    for (int it = 0; it < 6; ++it) {
      int rr = it * 8 + (htid >> 5);            // 0..47 = dt*16 + bb
      int dt = rr >> 4, bb = rr & 15;
      int lane32 = htid & 31, c = lane32 * 4;
      floatx4 v = {0.f, 0.f, 0.f, 0.f};
      if (t >= dt)
        v = *(const floatx4*)(x + ((size_t)(mt * 16 + bb) * SEQL + (t - dt)) * INDIM + c);
      int kk = dt * 4 + (c >> 5), qq = (c >> 3) & 3, j0 = c & 7;
      short4v pk;
#pragma unroll
      for (int j = 0; j < 4; ++j) pk[j] = f2bf(v[j]);
      *(short4v*)&xF[((kk * 64 + qq * 16 + bb) * 8) + j0] = pk;
    }
    __syncthreads();

    const int wvp = htid >> 6, lane = htid & 63, ln16 = lane & 15;
    const int qp = lane >> 4;

    short8 aF[12];
#pragma unroll
    for (int kk = 0; kk < 12; ++kk) aF[kk] = *(const short8*)&xF[(kk * 64 + lane) * 8];

    unsigned* slab = pre2 + (size_t)((mt * 4 + qp) * SEQL + t) * 1536;

#pragma unroll
    for (int ig = 0; ig < 3; ++ig) {
      const int ngrp = wvp * 3 + ig;               // 0..11 -> 64-col group
      const float sc = (ngrp >= 8) ? PL2E2 : NL2E;
      floatx4 acc[4];
#pragma unroll
      for (int nt = 0; nt < 4; ++nt) {
        float bv = bias[ngrp * 64 + nt * 16 + ln16] * sc;
#pragma unroll
        for (int r = 0; r < 4; ++r) acc[nt][r] = bv;
      }
#pragma unroll
      for (int kk = 0; kk < 12; ++kk) {
#pragma unroll
        for (int nt = 0; nt < 4; ++nt) {
          int n = ngrp * 64 + nt * 16 + ln16;
          short8 w = *(const short8*)(WcB + (((size_t)(n * 12 + kk) * 4 + qp) * 8));
          acc[nt] = __builtin_amdgcn_mfma_f32_16x16x32_bf16(aF[kk], w, acc[nt], 0, 0, 0);
        }
      }
      const int g = ngrp >> 2;                     // gate 0:r 1:u 2:h
#pragma unroll
      for (int p = 0; p < 2; ++p) {                // nt pair (2p, 2p+1)
        int wvc = (ngrp & 3) * 2 + p;              // consuming rnn wave
#pragma unroll
        for (int r = 0; r < 4; ++r) {
          unsigned lo = (unsigned)(unsigned short)f2bf(acc[2 * p][r]);
          unsigned hi = (unsigned)(unsigned short)f2bf(acc[2 * p + 1][r]);
          slab[g * 512 + wvc * 64 + r * 16 + ln16] = lo | (hi << 16);
        }
      }
    }

    __syncthreads();                               // all 512 threads' stores done
    if (tid == 0) {
      __threadfence();                             // L2 writeback: cross-XCD visible
      __hip_atomic_store(&flags[(2 * tpair) * 8 + mt], 1,
                         __ATOMIC_RELEASE, __HIP_MEMORY_SCOPE_AGENT);
      __hip_atomic_store(&flags[(2 * tpair + 1) * 8 + mt], 1,
                         __ATOMIC_RELEASE, __HIP_MEMORY_SCOPE_AGENT);
    }
    return;
  }

  // =================== rnn role: persistent recurrence ===================
  const int tid = threadIdx.x;
  const int wg = blockIdx.x;

  if (tid == 0) {   // publish CU key FIRST so proj blocks can detect us
    unsigned k = cu_key();
    __hip_atomic_store(&ctl[C_KEY + wg], (int)k, __ATOMIC_RELAXED,
                       __HIP_MEMORY_SCOPE_AGENT);
    __hip_atomic_fetch_add(&ctl[C_RDY], 1, __ATOMIC_RELEASE,
                           __HIP_MEMORY_SCOPE_AGENT);
  }

  __builtin_amdgcn_s_setprio(2);

  short* hFc = smem;                    // h,  rows 0..3 compact (4*HSTRIDE)
  short* rFc = smem + 4 * HSTRIDE;      // r*h

  const int wv = tid >> 6, lane = tid & 63, ln16 = lane & 15, q = lane >> 4;
  const int row4 = lane & 3;            // A-frag source row (m & 3)
  const int mtg = wg >> 2;              // producer mt group

  // persistent weight fragments: this wave's 32 cols of each gate
  short8 wR[2][8], wU[2][8], wH[2][8];
#pragma unroll
  for (int nt = 0; nt < 2; ++nt) {
    int nr = wv * 32 + nt * 16 + ln16;
#pragma unroll
    for (int kk = 0; kk < 8; ++kk) {
      wR[nt][kk] = *(const short8*)(WhB + (((size_t)(nr * 8 + kk) * 4 + q) * 8));
      wU[nt][kk] = *(const short8*)(WhB + (((size_t)((256 + nr) * 8 + kk) * 4 + q) * 8));
      wH[nt][kk] = *(const short8*)(WhB + (((size_t)((512 + nr) * 8 + kk) * 4 + q) * 8));
    }
  }
  for (int i = tid; i < 4 * HSTRIDE; i += 512) { hFc[i] = 0; rFc[i] = 0; }

  const floatx4 z4 = {0.f, 0.f, 0.f, 0.f};
  float hq[2] = {0.f, 0.f};             // h(row=q, col = wv*32 + nt*16 + ln16)

  const unsigned* slab0 = pre2 + (size_t)wg * SEQL * 1536;

  acq_spin(&flags[0 * 8 + mtg]);        // wait for slab 0
  unsigned cur0 = slab0[0 * 512 + tid];
  unsigned cur1 = slab0[1 * 512 + tid];
  unsigned cur2 = slab0[2 * 512 + tid];
  int fcur = __hip_atomic_load(&flags[1 * 8 + mtg],
                               __ATOMIC_RELAXED, __HIP_MEMORY_SCOPE_AGENT);

  float* outBase = out + ((size_t)(wg * 4 + q) * SEQL) * UNITS + wv * 32 + ln16;
  const int aoff = row4 * HSTRIDE + q * 8;       // + kk*32 per step
  const int woff = q * HSTRIDE + wv * 32 + ln16; // + nt*16

  __syncthreads();

  for (int t = 0; t < SEQL; ++t) {
    if (tid == 0)   // publish consumer progress for parked tail producers
      __hip_atomic_store(&ctl[C_PROG + wg], t, __ATOMIC_RELAXED,
                         __HIP_MEMORY_SCOPE_AGENT);
    // issue next-next flag read now; its result is needed only next iter
    int fnxt = 1;
    if (t + 2 < SEQL)
      fnxt = __hip_atomic_load(&flags[(t + 2) * 8 + mtg],
                               __ATOMIC_RELAXED, __HIP_MEMORY_SCOPE_AGENT);
    // gate for slab t+1 (value pipelined from last iteration; spin = rare)
    if (t + 1 < SEQL && fcur == 0) acq_spin(&flags[(t + 1) * 8 + mtg]);
    asm volatile("" ::: "memory");      // keep prefetch below the gate

    const unsigned* nslab = slab0 + (size_t)(t < SEQL - 1 ? t + 1 : t) * 1536;
    unsigned nxt0 = nslab[0 * 512 + tid];
    unsigned nxt1 = nslab[1 * 512 + tid];
    unsigned nxt2 = nslab[2 * 512 + tid];

    // ---- phase A: r,u pre-acts ----
    floatx4 accR[2], accU[2];
    {
      const short8 a0 = *(const short8*)&hFc[aoff];
      accR[0] = __builtin_amdgcn_mfma_f32_16x16x32_bf16(a0, wR[0][0], z4, 0, 0, 0);
      accR[1] = __builtin_amdgcn_mfma_f32_16x16x32_bf16(a0, wR[1][0], z4, 0, 0, 0);
      accU[0] = __builtin_amdgcn_mfma_f32_16x16x32_bf16(a0, wU[0][0], z4, 0, 0, 0);
      accU[1] = __builtin_amdgcn_mfma_f32_16x16x32_bf16(a0, wU[1][0], z4, 0, 0, 0);
    }
#pragma unroll
    for (int kk = 1; kk < 8; ++kk) {
      const short8 a = *(const short8*)&hFc[aoff + kk * 32];
      accR[0] = __builtin_amdgcn_mfma_f32_16x16x32_bf16(a, wR[0][kk], accR[0], 0, 0, 0);
      accR[1] = __builtin_amdgcn_mfma_f32_16x16x32_bf16(a, wR[1][kk], accR[1], 0, 0, 0);
      accU[0] = __builtin_amdgcn_mfma_f32_16x16x32_bf16(a, wU[0][kk], accU[0], 0, 0, 0);
      accU[1] = __builtin_amdgcn_mfma_f32_16x16x32_bf16(a, wU[1][kk], accU[1], 0, 0, 0);
    }
    float uq[2];
#pragma unroll
    for (int nt = 0; nt < 2; ++nt) {
      float vR = (q == 0) ? accR[nt][0] : (q == 1) ? accR[nt][1]
               : (q == 2) ? accR[nt][2] : accR[nt][3];
      float vU = (q == 0) ? accU[nt][0] : (q == 1) ? accU[nt][1]
               : (q == 2) ? accU[nt][2] : accU[nt][3];
      float pR = bf2f((unsigned short)(nt ? (cur0 >> 16) : (cur0 & 0xffff)));
      float pU = bf2f((unsigned short)(nt ? (cur1 >> 16) : (cur1 & 0xffff)));
      float rg = frcp(1.f + fexp2(vR + pR));
      uq[nt]   = frcp(1.f + fexp2(vU + pU));
      rFc[woff + nt * 16] = f2bf(rg * hq[nt]);
    }
    LDS_BARRIER();

    // ---- phase B: cand, h update ----
    floatx4 accH[2];
    {
      const short8 a0 = *(const short8*)&rFc[aoff];
      accH[0] = __builtin_amdgcn_mfma_f32_16x16x32_bf16(a0, wH[0][0], z4, 0, 0, 0);
      accH[1] = __builtin_amdgcn_mfma_f32_16x16x32_bf16(a0, wH[1][0], z4, 0, 0, 0);
    }
#pragma unroll
    for (int kk = 1; kk < 8; ++kk) {
      const short8 a = *(const short8*)&rFc[aoff + kk * 32];
      accH[0] = __builtin_amdgcn_mfma_f32_16x16x32_bf16(a, wH[0][kk], accH[0], 0, 0, 0);
      accH[1] = __builtin_amdgcn_mfma_f32_16x16x32_bf16(a, wH[1][kk], accH[1], 0, 0, 0);
    }
#pragma unroll
    for (int nt = 0; nt < 2; ++nt) {
      float vH = (q == 0) ? accH[nt][0] : (q == 1) ? accH[nt][1]
               : (q == 2) ? accH[nt][2] : accH[nt][3];
      float pH = bf2f((unsigned short)(nt ? (cur2 >> 16) : (cur2 & 0xffff)));
      float cand = 1.f - 2.f * frcp(1.f + fexp2(vH + pH));   // tanh (scale folded)
      float hnew = uq[nt] * (hq[nt] - cand) + cand;
      hq[nt] = hnew;
      hFc[woff + nt * 16] = f2bf(hnew);
      outBase[(size_t)t * UNITS + nt * 16] = hnew;
    }
    cur0 = nxt0; cur1 = nxt1; cur2 = nxt2; fcur = fnxt;
    LDS_BARRIER();
  }
}

extern "C" void kernel_launch(void* const* d_in, const int* in_sizes, int n_in,
                              void* d_out, int out_size, void* d_ws, size_t ws_size,
                              hipStream_t stream) {
  const float* x    = (const float*)d_in[0];
  const float* iw   = (const float*)d_in[1];
  const float* hw   = (const float*)d_in[2];
  const float* bias = (const float*)d_in[3];
  // d_in[4] (constant) is [I;0] — folded analytically, unused.
  float* out = (float*)d_out;

  unsigned* pre2 = (unsigned*)d_ws;                    // 32*1024*1536 dwords = 192 MB
  const size_t preDwords = (size_t)32 * SEQL * 1536;
  short* WcB = (short*)(pre2 + preDwords);             // 384*768 bf16
  short* WhB = WcB + (size_t)384 * G3;                 // 256*768 bf16
  int* flags = (int*)(WhB + (size_t)256 * G3);         // 8192 flags + 128 ctl

  prep_kernel<<<1953, 256, 0, stream>>>(iw, hw, WcB, WhB, flags);
  fused_kernel<<<32 + 4096, 512, 0, stream>>>(x, WcB, bias, pre2, WhB, out, flags);
}

// Round 7
// 1406.776 us; speedup vs baseline: 1.1567x; 1.1567x over previous
//
#include <hip/hip_runtime.h>

#define SEQL 1024
#define BATCHN 128
#define UNITS 256
#define INDIM 128
#define G3 768   // r|u|h gate columns

typedef __attribute__((ext_vector_type(8))) short short8;
typedef __attribute__((ext_vector_type(4))) short short4v;
typedef __attribute__((ext_vector_type(4))) float floatx4;

#define NL2E  -1.4426950408889634f   // -log2(e): r,u gate scale
#define PL2E2  2.8853900817779268f   //  2*log2(e): h gate scale

#define HSTRIDE 272                  // compact h row stride (shorts), breaks bank alias

__device__ __forceinline__ short f2bf(float f) {
  unsigned u = __float_as_uint(f);
  u += 0x7fff + ((u >> 16) & 1);   // round-to-nearest-even
  return (short)(u >> 16);
}
__device__ __forceinline__ float bf2f(unsigned short s) {
  return __uint_as_float(((unsigned)s) << 16);
}
__device__ __forceinline__ float fexp2(float x) {
#if __has_builtin(__builtin_amdgcn_exp2f)
  return __builtin_amdgcn_exp2f(x);
#else
  return __expf(0.6931471805599453f * x);
#endif
}
__device__ __forceinline__ float frcp(float x) {
#if __has_builtin(__builtin_amdgcn_rcpf)
  return __builtin_amdgcn_rcpf(x);
#else
  return 1.f / x;
#endif
}

// LDS-only barrier: orders ds ops without draining vmcnt.
#define LDS_BARRIER() do {                                   \
    asm volatile("s_waitcnt lgkmcnt(0)" ::: "memory");       \
    __builtin_amdgcn_s_barrier();                            \
    asm volatile("" ::: "memory");                           \
  } while (0)

// Acquire-spin on a producer flag.
__device__ __forceinline__ void acq_spin(const int* p) {
  while (__hip_atomic_load(p, __ATOMIC_ACQUIRE, __HIP_MEMORY_SCOPE_AGENT) == 0)
    __builtin_amdgcn_s_sleep(8);
}

// ---------------------------------------------------------------------------
// Kernel A: weight prep (unchanged math) + zeroing the 1024 producer flags.
// ---------------------------------------------------------------------------
__global__ void prep_kernel(const float* __restrict__ iw,   // (128,1792)
                            const float* __restrict__ hw,   // (256,768)
                            short* __restrict__ WcB, short* __restrict__ WhB,
                            int* __restrict__ flags) {
  int idx = blockIdx.x * 256 + threadIdx.x;
  const int WCN = 384 * G3;
  if (idx < WCN) {
    int k = idx / G3, n = idx % G3;
    int i = k & 127, blkk = k >> 7;      // 0:x_t 1:x_{t-1} 2:x_{t-2}
    int gsel = n >> 8, c = n & 255;      // 0:r 1:u 2:h
    const float* row = iw + (size_t)i * 1792;
    float v;
    if (blkk == 0) {
      v = (gsel == 0) ? row[c] + row[768 + c] + row[1280 + c]
        : (gsel == 1) ? row[256 + c] + row[1024 + c] + row[1536 + c]
                      : row[512 + c];
    } else if (blkk == 1) {
      v = (gsel == 0) ? -(row[768 + c] + 2.f * row[1280 + c])
        : (gsel == 1) ? -(row[1024 + c] + 2.f * row[1536 + c])
                      : 0.f;
    } else {
      v = (gsel == 0) ? row[1280 + c]
        : (gsel == 1) ? row[1536 + c]
                      : 0.f;
    }
    v *= (gsel == 2) ? PL2E2 : NL2E;
    int kk = k >> 5, q = (k >> 3) & 3, j = k & 7;
    WcB[(((n * 12 + kk) * 4 + q) * 8) + j] = f2bf(v);
  } else {
    idx -= WCN;
    if (idx < 256 * G3) {
      int k = idx / G3, n = idx % G3;
      float v = hw[(size_t)k * G3 + n] * ((n >> 8) == 2 ? PL2E2 : NL2E);
      int kk = k >> 5, q = (k >> 3) & 3, j = k & 7;
      WhB[(((n * 8 + kk) * 4 + q) * 8) + j] = f2bf(v);
    } else {
      idx -= 256 * G3;
      if (idx < SEQL) flags[idx] = 0;
    }
  }
}

// ---------------------------------------------------------------------------
// Fused kernel, 1 block/CU enforced by ~100 KB static LDS:
//  blocks 0..31  : persistent recurrence (consumer) — EXCLUSIVE CU each.
//  blocks 32..1055: input projection, ONE block per timestep t, M=128 (full
//  batch). A-frags for all 128 rows staged once in 96 KB LDS; each weight
//  fragment (held in regs, 256-VGPR cap via launch_bounds(512,1)) is reused
//  across 8 m-tiles -> 8x fewer L2 weight reads than the 16-row version.
//  Slab format identical to R4 (row-in-wg = C-reg r; wvc = (c_lo&255)>>5).
//  Handoff: flags[t] release-stored after threadfence; consumer pipelines
//  the flag read one step ahead with acquire-spin slow path.
// ---------------------------------------------------------------------------
__global__ __launch_bounds__(512, 1) void fused_kernel(
    const float* __restrict__ x, const short* __restrict__ WcB,
    const float* __restrict__ bias, unsigned* __restrict__ pre2,
    const short* __restrict__ WhB, float* __restrict__ out,
    int* __restrict__ flags) {
  __shared__ __align__(16) short xA[6144 * 8];       // 96 KB proj A-frags
  __shared__ __align__(16) short hFc[4 * HSTRIDE];   // rnn h (2.1 KB)
  __shared__ __align__(16) short rFc[4 * HSTRIDE];   // rnn r*h (2.1 KB)

  const int tid = threadIdx.x;

  if (blockIdx.x >= 32) {
    // =================== proj role: one block per t, M=128 ===================
    const int t = blockIdx.x - 32;

    // stage A[m][k] = x_hist[m][k] as MFMA A-frags for all 128 rows:
    // unit u (short8) holds A[mi*16+bb][kk*32+qq*8 .. +7] at xA[u*8],
    // u = (kk*8+mi)*64 + qq*16 + bb  (read addr: (kk*8+mi)*64 + lane).
#pragma unroll
    for (int it = 0; it < 12; ++it) {
      int u = it * 512 + tid;
      int kk8mi = u >> 6, l6 = u & 63;
      int kk = kk8mi >> 3, mi = kk8mi & 7;
      int qq = l6 >> 4, bb = l6 & 15;
      int row = mi * 16 + bb;
      int k = kk * 32 + qq * 8;
      int dt = k >> 7, kin = k & 127;          // dt: 0=x_t 1=x_{t-1} 2=x_{t-2}
      floatx4 v0 = {0.f, 0.f, 0.f, 0.f}, v1 = {0.f, 0.f, 0.f, 0.f};
      if (t >= dt) {
        const float* src = x + ((size_t)row * SEQL + (t - dt)) * INDIM + kin;
        v0 = *(const floatx4*)src;
        v1 = *(const floatx4*)(src + 4);
      }
      short8 pk;
#pragma unroll
      for (int j = 0; j < 4; ++j) { pk[j] = f2bf(v0[j]); pk[4 + j] = f2bf(v1[j]); }
      *(short8*)&xA[u * 8] = pk;
    }
    __syncthreads();

    const int w = tid >> 6, lane = tid & 63, ln16 = lane & 15, qp = lane >> 4;

    // wave w owns cols [w*96, w*96+96): 3 chunks of one col-pair (c, c+16)
#pragma unroll
    for (int j = 0; j < 3; ++j) {
      const int n0 = w * 96 + 32 * j;            // pair base (bit4 == 0)
      const int nA = n0 + ln16, nB = n0 + 16 + ln16;
      const int g = n0 >> 8;                     // gate 0:r 1:u 2:h
      const float sc = (g == 2) ? PL2E2 : NL2E;
      const int wvc = (n0 & 255) >> 5;           // consuming rnn wave

      short8 wA[12], wB[12];                     // resident weight frags
#pragma unroll
      for (int kk = 0; kk < 12; ++kk) {
        wA[kk] = *(const short8*)(WcB + (((size_t)(nA * 12 + kk) * 4 + qp) * 8));
        wB[kk] = *(const short8*)(WcB + (((size_t)(nB * 12 + kk) * 4 + qp) * 8));
      }
      const float bvA = bias[nA] * sc, bvB = bias[nB] * sc;

#pragma unroll
      for (int mi = 0; mi < 8; ++mi) {           // 8 m-tiles reuse wA/wB
        floatx4 aA = {bvA, bvA, bvA, bvA};
        floatx4 aB = {bvB, bvB, bvB, bvB};
#pragma unroll
        for (int kk = 0; kk < 12; ++kk) {
          const short8 a = *(const short8*)&xA[(((kk * 8 + mi) * 64) + lane) * 8];
          aA = __builtin_amdgcn_mfma_f32_16x16x32_bf16(a, wA[kk], aA, 0, 0, 0);
          aB = __builtin_amdgcn_mfma_f32_16x16x32_bf16(a, wB[kk], aB, 0, 0, 0);
        }
        // batch row = mi*16 + qp*4 + r  ->  rnn wg = mi*4+qp, row-in-wg = r
        unsigned* slab = pre2 + (size_t)((mi * 4 + qp) * SEQL + t) * 1536
                       + g * 512 + wvc * 64 + ln16;
#pragma unroll
        for (int r = 0; r < 4; ++r) {
          unsigned lo = (unsigned)(unsigned short)f2bf(aA[r]);
          unsigned hi = (unsigned)(unsigned short)f2bf(aB[r]);
          slab[r * 16] = lo | (hi << 16);
        }
      }
    }

    __syncthreads();                             // all stores issued
    if (tid == 0) {
      __threadfence();                           // L2 writeback: cross-XCD visible
      __hip_atomic_store(&flags[t], 1, __ATOMIC_RELEASE, __HIP_MEMORY_SCOPE_AGENT);
    }
    return;
  }

  // =================== rnn role: persistent recurrence ===================
  const int wv = tid >> 6, lane = tid & 63, ln16 = lane & 15, q = lane >> 4;
  const int row4 = lane & 3;            // A-frag source row (m & 3)
  const int wg = blockIdx.x;

  // persistent weight fragments: this wave's 32 cols of each gate
  // (256-VGPR cap under launch_bounds(512,1): 192 frag regs can stay live)
  short8 wR[2][8], wU[2][8], wH[2][8];
#pragma unroll
  for (int nt = 0; nt < 2; ++nt) {
    int nr = wv * 32 + nt * 16 + ln16;
#pragma unroll
    for (int kk = 0; kk < 8; ++kk) {
      wR[nt][kk] = *(const short8*)(WhB + (((size_t)(nr * 8 + kk) * 4 + q) * 8));
      wU[nt][kk] = *(const short8*)(WhB + (((size_t)((256 + nr) * 8 + kk) * 4 + q) * 8));
      wH[nt][kk] = *(const short8*)(WhB + (((size_t)((512 + nr) * 8 + kk) * 4 + q) * 8));
    }
  }
  for (int i = tid; i < 4 * HSTRIDE; i += 512) { hFc[i] = 0; rFc[i] = 0; }

  const floatx4 z4 = {0.f, 0.f, 0.f, 0.f};
  float hq[2] = {0.f, 0.f};             // h(row=q, col = wv*32 + nt*16 + ln16)

  const unsigned* slab0 = pre2 + (size_t)wg * SEQL * 1536;

  acq_spin(&flags[0]);                  // wait for slab 0
  unsigned cur0 = slab0[0 * 512 + tid];
  unsigned cur1 = slab0[1 * 512 + tid];
  unsigned cur2 = slab0[2 * 512 + tid];
  int fcur = __hip_atomic_load(&flags[1], __ATOMIC_RELAXED, __HIP_MEMORY_SCOPE_AGENT);

  float* outBase = out + ((size_t)(wg * 4 + q) * SEQL) * UNITS + wv * 32 + ln16;
  const int aoff = row4 * HSTRIDE + q * 8;       // + kk*32 per step
  const int woff = q * HSTRIDE + wv * 32 + ln16; // + nt*16

  __syncthreads();

  for (int t = 0; t < SEQL; ++t) {
    // issue next-next flag read now; its result is needed only next iter
    int fnxt = 1;
    if (t + 2 < SEQL)
      fnxt = __hip_atomic_load(&flags[t + 2], __ATOMIC_RELAXED, __HIP_MEMORY_SCOPE_AGENT);
    // gate for slab t+1 (value pipelined from last iteration; spin = rare)
    if (t + 1 < SEQL && fcur == 0) acq_spin(&flags[t + 1]);
    asm volatile("" ::: "memory");      // keep prefetch below the gate

    const unsigned* nslab = slab0 + (size_t)(t < SEQL - 1 ? t + 1 : t) * 1536;
    unsigned nxt0 = nslab[0 * 512 + tid];
    unsigned nxt1 = nslab[1 * 512 + tid];
    unsigned nxt2 = nslab[2 * 512 + tid];

    // ---- phase A: r,u pre-acts ----
    floatx4 accR[2], accU[2];
    {
      const short8 a0 = *(const short8*)&hFc[aoff];
      accR[0] = __builtin_amdgcn_mfma_f32_16x16x32_bf16(a0, wR[0][0], z4, 0, 0, 0);
      accR[1] = __builtin_amdgcn_mfma_f32_16x16x32_bf16(a0, wR[1][0], z4, 0, 0, 0);
      accU[0] = __builtin_amdgcn_mfma_f32_16x16x32_bf16(a0, wU[0][0], z4, 0, 0, 0);
      accU[1] = __builtin_amdgcn_mfma_f32_16x16x32_bf16(a0, wU[1][0], z4, 0, 0, 0);
    }
#pragma unroll
    for (int kk = 1; kk < 8; ++kk) {
      const short8 a = *(const short8*)&hFc[aoff + kk * 32];
      accR[0] = __builtin_amdgcn_mfma_f32_16x16x32_bf16(a, wR[0][kk], accR[0], 0, 0, 0);
      accR[1] = __builtin_amdgcn_mfma_f32_16x16x32_bf16(a, wR[1][kk], accR[1], 0, 0, 0);
      accU[0] = __builtin_amdgcn_mfma_f32_16x16x32_bf16(a, wU[0][kk], accU[0], 0, 0, 0);
      accU[1] = __builtin_amdgcn_mfma_f32_16x16x32_bf16(a, wU[1][kk], accU[1], 0, 0, 0);
    }
    float uq[2];
#pragma unroll
    for (int nt = 0; nt < 2; ++nt) {
      float vR = (q == 0) ? accR[nt][0] : (q == 1) ? accR[nt][1]
               : (q == 2) ? accR[nt][2] : accR[nt][3];
      float vU = (q == 0) ? accU[nt][0] : (q == 1) ? accU[nt][1]
               : (q == 2) ? accU[nt][2] : accU[nt][3];
      float pR = bf2f((unsigned short)(nt ? (cur0 >> 16) : (cur0 & 0xffff)));
      float pU = bf2f((unsigned short)(nt ? (cur1 >> 16) : (cur1 & 0xffff)));
      float rg = frcp(1.f + fexp2(vR + pR));
      uq[nt]   = frcp(1.f + fexp2(vU + pU));
      rFc[woff + nt * 16] = f2bf(rg * hq[nt]);
    }
    LDS_BARRIER();

    // ---- phase B: cand, h update ----
    floatx4 accH[2];
    {
      const short8 a0 = *(const short8*)&rFc[aoff];
      accH[0] = __builtin_amdgcn_mfma_f32_16x16x32_bf16(a0, wH[0][0], z4, 0, 0, 0);
      accH[1] = __builtin_amdgcn_mfma_f32_16x16x32_bf16(a0, wH[1][0], z4, 0, 0, 0);
    }
#pragma unroll
    for (int kk = 1; kk < 8; ++kk) {
      const short8 a = *(const short8*)&rFc[aoff + kk * 32];
      accH[0] = __builtin_amdgcn_mfma_f32_16x16x32_bf16(a, wH[0][kk], accH[0], 0, 0, 0);
      accH[1] = __builtin_amdgcn_mfma_f32_16x16x32_bf16(a, wH[1][kk], accH[1], 0, 0, 0);
    }
#pragma unroll
    for (int nt = 0; nt < 2; ++nt) {
      float vH = (q == 0) ? accH[nt][0] : (q == 1) ? accH[nt][1]
               : (q == 2) ? accH[nt][2] : accH[nt][3];
      float pH = bf2f((unsigned short)(nt ? (cur2 >> 16) : (cur2 & 0xffff)));
      float cand = 1.f - 2.f * frcp(1.f + fexp2(vH + pH));   // tanh (scale folded)
      float hnew = uq[nt] * (hq[nt] - cand) + cand;
      hq[nt] = hnew;
      hFc[woff + nt * 16] = f2bf(hnew);
      outBase[(size_t)t * UNITS + nt * 16] = hnew;
    }
    cur0 = nxt0; cur1 = nxt1; cur2 = nxt2; fcur = fnxt;
    LDS_BARRIER();
  }
}

extern "C" void kernel_launch(void* const* d_in, const int* in_sizes, int n_in,
                              void* d_out, int out_size, void* d_ws, size_t ws_size,
                              hipStream_t stream) {
  const float* x    = (const float*)d_in[0];
  const float* iw   = (const float*)d_in[1];
  const float* hw   = (const float*)d_in[2];
  const float* bias = (const float*)d_in[3];
  // d_in[4] (constant) is [I;0] — folded analytically, unused.
  float* out = (float*)d_out;

  unsigned* pre2 = (unsigned*)d_ws;                    // 32*1024*1536 dwords = 192 MB
  const size_t preDwords = (size_t)32 * SEQL * 1536;
  short* WcB = (short*)(pre2 + preDwords);             // 384*768 bf16
  short* WhB = WcB + (size_t)384 * G3;                 // 256*768 bf16
  int* flags = (int*)(WhB + (size_t)256 * G3);         // 1024 ints

  prep_kernel<<<1952, 256, 0, stream>>>(iw, hw, WcB, WhB, flags);
  fused_kernel<<<32 + 1024, 512, 0, stream>>>(x, WcB, bias, pre2, WhB, out, flags);
}